// Round 11
// baseline (383.000 us; speedup 1.0000x reference)
//
#include <hip/hip_runtime.h>

typedef _Float16 f16;
typedef f16 f16x2 __attribute__((ext_vector_type(2)));
typedef f16 f16x4 __attribute__((ext_vector_type(4)));
typedef f16 f16x8 __attribute__((ext_vector_type(8)));
typedef float f32x4 __attribute__((ext_vector_type(4)));

union v8split { f16x8 v8; f16x2 v2[4]; };

// ---------------- d_ws layout ----------------
#define WQH_OFF 0
#define WPH_OFF (768 * 256 * 2)                         // 393216
#define XW_OFF  (WPH_OFF + 256 * 256 * 2)               // 524288
#define O2_OFF  (XW_OFF + (size_t)2048 * 16384 * 2)     // +67108864
#define WS_NEED (O2_OFF + (size_t)2048 * 16384 * 2)     // 134742016

// LDS (half-window block): xw/out2 tile [32][512B] = 16KB | qkv [32t][1536B]
// = 48KB  -> 64KB total -> 2 blocks/CU, 16 waves/CU (4/SIMD).
#define QKV_LDS_OFF 16384
#define SMEM_TOTAL 65536

// fp32 -> fp16 weight conversion
__global__ __launch_bounds__(256) void cvt_weights_k(
    const float* __restrict__ wq, const float* __restrict__ wp,
    f16* __restrict__ wq_h, f16* __restrict__ wp_h) {
  int idx = blockIdx.x * 256 + threadIdx.x;
  if (idx < 768 * 256) wq_h[idx] = (f16)wq[idx];
  else wp_h[idx - 768 * 256] = (f16)wp[idx - 768 * 256];
}

// XOR-swizzled addr into a 32-row x 512B tile (xw / out2).
__device__ __forceinline__ char* xwp(char* s, int row, int colbyte) {
  return s + row * 512 + (colbyte ^ (((row ^ (row >> 3)) & 7) << 4));
}
// qkv tile [32 t][768 f], row stride 1536B.
__device__ __forceinline__ char* qvp(char* s, int t, int fbyte) {
  return s + QKV_LDS_OFF + t * 1536 + (fbyte ^ ((t & 7) << 4));
}

// DPP quad_perm swaps: lane^1 and lane^2
__device__ __forceinline__ float qswap1f(float v) {
  int x = __builtin_bit_cast(int, v);
  x = __builtin_amdgcn_update_dpp(0, x, 0xB1, 0xf, 0xf, true);  // [1,0,3,2]
  return __builtin_bit_cast(float, x);
}
__device__ __forceinline__ float qswap2f(float v) {
  int x = __builtin_bit_cast(int, v);
  x = __builtin_amdgcn_update_dpp(0, x, 0x4E, 0xf, 0xf, true);  // [2,3,0,1]
  return __builtin_bit_cast(float, x);
}

#if __has_builtin(__builtin_amdgcn_fdot2)
__device__ __forceinline__ float fdot2f(f16x2 a, f16x2 b, float c) {
  return __builtin_amdgcn_fdot2(a, b, c, false);
}
#else
__device__ __forceinline__ float fdot2f(f16x2 a, f16x2 b, float c) {
  return c + (float)a[0] * (float)b[0] + (float)a[1] * (float)b[1];
}
#endif

// ---- K1: gather/transpose x (fp32 strided, full 128B-line reads) -> xw_all
// (fp16, per-HALF-WINDOW contiguous 16KB tiles, PRE-SWIZZLED to match xwp).
__global__ __launch_bounds__(256) void gather_k(const float* __restrict__ x,
                                                f16* __restrict__ xw_all) {
  const int g = blockIdx.x >> 4, cb = blockIdx.x & 15;
  const int b = g >> 6, iw = (g >> 3) & 7, jw = g & 7;
  const int tid = threadIdx.x;
  const int c = cb * 16 + (tid >> 4), a = (tid >> 2) & 3, bb = tid & 3;
  const float* src = x + (size_t)b * 8388608 + (size_t)c * 32768 +
                     (iw * 4 + a) * 1024 + (jw * 4 + bb) * 32;
  const int t = c >> 2, hb = t >> 5, tl = t & 31;
  const int c2b = (c & 3) * 128 + a * 32 + bb * 8;
  const int byt = tl * 512 + (c2b ^ (((tl ^ (tl >> 3)) & 7) << 4));
  // halfwin index at kw=0 is g*16 + hb; each kw adds 2 tiles = 32768 B.
  char* wbase = (char*)(xw_all + (size_t)(g * 16 + hb) * 8192) + byt;
#pragma unroll
  for (int kw = 0; kw < 8; ++kw) {
    float4 v = *(const float4*)(src + kw * 4);
    f16x4 h;
    h[0] = (f16)v.x; h[1] = (f16)v.y; h[2] = (f16)v.z; h[3] = (f16)v.w;
    *(f16x4*)(wbase + (size_t)kw * 32768) = h;
  }
}

// ---- K2: fused half-window kernel (32 tokens). One block per half-window,
// 4096 blocks, 64KB LDS -> 2 blocks/CU. Phases: xw->LDS, GEMM1, per-token
// attention, GEMM2 -> o2T.
__global__ __launch_bounds__(512) void win_attn_k(
    const f16* __restrict__ xw_all, const f16* __restrict__ wq_h,
    const f16* __restrict__ wp_h, f16* __restrict__ o2T) {
  extern __shared__ char smem[];
  const int hw = blockIdx.x;              // half-window id
  const int wi = hw >> 1, hb = hw & 1;    // window, half (tokens hb*32..+32)
  const int tid = threadIdx.x, wv = tid >> 6, lane = tid & 63;
  const int lcol = lane & 15, lq = lane >> 4;

  // Phase 1: 16KB pre-swizzled xw tile -> LDS (linear dest, 2x16B/thread).
  {
    const char* g = (const char*)(xw_all + (size_t)hw * 8192) + tid * 16;
#pragma unroll
    for (int i = 0; i < 2; ++i)
      __builtin_amdgcn_global_load_lds(
          (const __attribute__((address_space(1))) void*)(g + i * 8192),
          (__attribute__((address_space(3))) void*)(smem + tid * 16 + i * 8192),
          16, 0, 0);
  }
  __syncthreads();

  // Phase 2: GEMM1 qkv[32t x 768f]. Wave = 96 f-cols; acc[3][2] per half.
#pragma unroll 1
  for (int half = 0; half < 2; ++half) {
    f32x4 acc[3][2] = {};
    const int fs = wv * 96 + half * 48;
#pragma unroll
    for (int kt = 0; kt < 8; ++kt) {
      f16x8 bf[2];
#pragma unroll
      for (int nt = 0; nt < 2; ++nt)
        bf[nt] = *(const f16x8*)xwp(smem, nt * 16 + lcol, kt * 64 + lq * 16);
#pragma unroll
      for (int ms = 0; ms < 3; ++ms) {
        f16x8 af = *(const f16x8*)(wq_h + (size_t)(fs + ms * 16 + lcol) * 256 + kt * 32 + lq * 8);
#pragma unroll
        for (int nt = 0; nt < 2; ++nt)
          acc[ms][nt] = __builtin_amdgcn_mfma_f32_16x16x32_f16(af, bf[nt], acc[ms][nt], 0, 0, 0);
      }
    }
    // D: col(lane&15)=local token, row(lq*4+r)=feature -> f16x4 qkv[t][f].
#pragma unroll
    for (int ms = 0; ms < 3; ++ms)
#pragma unroll
      for (int nt = 0; nt < 2; ++nt) {
        f16x4 hv;
        hv[0] = (f16)acc[ms][nt][0]; hv[1] = (f16)acc[ms][nt][1];
        hv[2] = (f16)acc[ms][nt][2]; hv[3] = (f16)acc[ms][nt][3];
        *(f16x4*)qvp(smem, nt * 16 + lcol, (fs + ms * 16 + lq * 4) * 2) = hv;
      }
  }
  __syncthreads();

  // Phase 3: per-token attention. Wave owns 4 tokens; lane = (tt<<4|h<<2|dq):
  // each lane covers a 16-half d-quarter; S merged via lane^1 then lane^2.
  {
    const int tt = lane >> 4, h = (lane >> 2) & 3, dq = lane & 3;
    const int tl = wv * 4 + tt;
    const int db = dq * 32;  // byte offset of this lane's d-quarter

    f16x2 q2[8];
#pragma unroll
    for (int j = 0; j < 2; ++j) {
      v8split u;
      u.v8 = *(const f16x8*)qvp(smem, tl, h * 128 + db + j * 16);
      q2[j * 4 + 0] = u.v2[0]; q2[j * 4 + 1] = u.v2[1];
      q2[j * 4 + 2] = u.v2[2]; q2[j * 4 + 3] = u.v2[3];
    }
    float s[4];
#pragma unroll
    for (int g = 0; g < 4; ++g) {
      float a = 0.f;
#pragma unroll
      for (int j = 0; j < 2; ++j) {
        v8split u;
        u.v8 = *(const f16x8*)qvp(smem, tl, 512 + g * 128 + db + j * 16);
        a = fdot2f(q2[j * 4 + 0], u.v2[0], a);
        a = fdot2f(q2[j * 4 + 1], u.v2[1], a);
        a = fdot2f(q2[j * 4 + 2], u.v2[2], a);
        a = fdot2f(q2[j * 4 + 3], u.v2[3], a);
      }
      s[g] = a;
    }
#pragma unroll
    for (int g = 0; g < 4; ++g) {
      s[g] += qswap1f(s[g]);   // merge dq^1
      s[g] += qswap2f(s[g]);   // merge dq^2 -> full 64-d dot on all 4 lanes
    }

    float mx = -1e30f;
#pragma unroll
    for (int g = 0; g < 4; ++g) {
      float v = fminf(fmaxf(s[g] * 0.125f, -10.f), 10.f);  // clip BEFORE softmax
      s[g] = v; mx = fmaxf(mx, v);
    }
    float sum = 0.f;
#pragma unroll
    for (int g = 0; g < 4; ++g) { s[g] = __expf(s[g] - mx); sum += s[g]; }
    float inv = 1.f / sum;
#pragma unroll
    for (int g = 0; g < 4; ++g) s[g] *= inv;

    float o[16] = {};
#pragma unroll
    for (int g = 0; g < 4; ++g) {
      float p = s[g];
#pragma unroll
      for (int j = 0; j < 2; ++j) {
        v8split u;
        u.v8 = *(const f16x8*)qvp(smem, tl, 1024 + g * 128 + db + j * 16);
#pragma unroll
        for (int i = 0; i < 4; ++i) {
          o[j * 8 + 2 * i]     += p * (float)u.v2[i][0];
          o[j * 8 + 2 * i + 1] += p * (float)u.v2[i][1];
        }
      }
    }
    // out2 tile row_local = h*8 + tl/4, colbyte = (tl&3)*128 + dq*32 + j*16.
    const int row = h * 8 + (tl >> 2);
    const int cb0 = (tl & 3) * 128 + db;
#pragma unroll
    for (int j = 0; j < 2; ++j) {
      f16x8 ov;
      ov[0] = (f16)o[j * 8 + 0]; ov[1] = (f16)o[j * 8 + 1];
      ov[2] = (f16)o[j * 8 + 2]; ov[3] = (f16)o[j * 8 + 3];
      ov[4] = (f16)o[j * 8 + 4]; ov[5] = (f16)o[j * 8 + 5];
      ov[6] = (f16)o[j * 8 + 6]; ov[7] = (f16)o[j * 8 + 7];
      *(f16x8*)xwp(smem, row, cb0 + j * 16) = ov;
    }
  }
  __syncthreads();

  // Phase 4: GEMM2 on the 32-row out2 tile. Wave = 32 c3 cols.
  // Tile row i corresponds to global t2 = (i>>3)*16 + hb*8 + (i&7).
  {
    f32x4 acc2[2][2] = {};
#pragma unroll
    for (int kt = 0; kt < 8; ++kt) {
      f16x8 afr[2];
#pragma unroll
      for (int mt = 0; mt < 2; ++mt)
        afr[mt] = *(const f16x8*)xwp(smem, mt * 16 + lcol, kt * 64 + lq * 16);
#pragma unroll
      for (int nt = 0; nt < 2; ++nt) {
        f16x8 bfr = *(const f16x8*)(wp_h + (size_t)(wv * 32 + nt * 16 + lcol) * 256 + kt * 32 + lq * 8);
#pragma unroll
        for (int mt = 0; mt < 2; ++mt)
          acc2[mt][nt] = __builtin_amdgcn_mfma_f32_16x16x32_f16(afr[mt], bfr, acc2[mt][nt], 0, 0, 0);
      }
    }
    // D row i = mt*16 + lq*4 + r  ->  t2 = (mt*2+(lq>>1))*16 + hb*8 + (lq&1)*4 + r
    f16* ob = o2T + (size_t)wi * 16384;
    const int t2b = hb * 8 + ((lq & 1) * 4);
#pragma unroll
    for (int mt = 0; mt < 2; ++mt)
#pragma unroll
      for (int nt = 0; nt < 2; ++nt) {
        int c3 = wv * 32 + nt * 16 + lcol;
        int t2 = (mt * 2 + (lq >> 1)) * 16 + t2b;
        f16x4 hv;
        hv[0] = (f16)acc2[mt][nt][0]; hv[1] = (f16)acc2[mt][nt][1];
        hv[2] = (f16)acc2[mt][nt][2]; hv[3] = (f16)acc2[mt][nt][3];
        *(f16x4*)(ob + c3 * 64 + t2) = hv;
      }
  }
}

// ---- K3: scatter o2T (fp16, L3-hot) -> out (fp32, full 128B-line writes).
__global__ __launch_bounds__(256) void scatter_k(const f16* __restrict__ o2T,
                                                 float* __restrict__ out) {
  const int g = blockIdx.x >> 4, cb = blockIdx.x & 15;
  const int b = g >> 6, iw = (g >> 3) & 7, jw = g & 7;
  const int tid = threadIdx.x;
  const int c3 = cb * 16 + (tid >> 4), a = (tid >> 2) & 3, bb = tid & 3;
  const f16* rbase = o2T + (size_t)(g << 3) * 16384 + c3 * 64 + a * 16 + bb * 4;
  float* dst = out + (size_t)b * 8388608 + (size_t)c3 * 32768 +
               (iw * 4 + a) * 1024 + (jw * 4 + bb) * 32;
#pragma unroll
  for (int kw = 0; kw < 8; ++kw) {
    f16x4 h = *(const f16x4*)(rbase + kw * 16384);
    float4 v;
    v.x = (float)h[0]; v.y = (float)h[1]; v.z = (float)h[2]; v.w = (float)h[3];
    *(float4*)(dst + kw * 4) = v;
  }
}

// ================= fallback: round-1 fused kernel (validated, ws-light) =====
#define FB_LDQ 68
#define FB_QKV_OFF 32768
#define FB_SPART_OFF (FB_QKV_OFF + 768 * FB_LDQ * 2)
#define FB_SMEM (FB_SPART_OFF + 32 * 64 * 4)

__device__ __forceinline__ char* fb_xwp(char* s, int row, int colbyte) {
  return s + row * 512 + (colbyte ^ ((row & 7) << 4));
}

__global__ __launch_bounds__(512) void fused_fb_k(
    const float* __restrict__ x, const f16* __restrict__ wq_h,
    const f16* __restrict__ wp_h, float* __restrict__ out) {
  extern __shared__ char smem[];
  f16* qkvT = (f16*)(smem + FB_QKV_OFF);
  float* spart = (float*)(smem + FB_SPART_OFF);
  const int tid = threadIdx.x;
  const int wi = blockIdx.x;
  const int kw = wi & 7, jw = (wi >> 3) & 7, iw = (wi >> 6) & 7, bw = wi >> 9;
  const float* xb = x + (size_t)bw * 8388608 + iw * 4096 + jw * 128 + kw * 4;
#pragma unroll
  for (int it = 0; it < 8; ++it) {
    int idx = it * 512 + tid;
    int c = idx >> 4, a = (idx >> 2) & 3, bb = idx & 3;
    float4 v = *(const float4*)(xb + (size_t)c * 32768 + a * 1024 + bb * 32);
    f16x4 h;
    h[0] = (f16)v.x; h[1] = (f16)v.y; h[2] = (f16)v.z; h[3] = (f16)v.w;
    *(f16x4*)fb_xwp(smem, c >> 2, (c & 3) * 128 + a * 32 + bb * 8) = h;
  }
  __syncthreads();
  const int wv = tid >> 6, lane = tid & 63;
  const int lcol = lane & 15, lq = lane >> 4;
  for (int nc = 0; nc < 2; ++nc) {
    const int ncb = wv * 96 + nc * 48;
    f32x4 acc[4][3] = {};
    for (int kt = 0; kt < 8; ++kt) {
      f16x8 afr[4];
#pragma unroll
      for (int mt = 0; mt < 4; ++mt)
        afr[mt] = *(const f16x8*)fb_xwp(smem, mt * 16 + lcol, kt * 64 + lq * 16);
#pragma unroll
      for (int nt = 0; nt < 3; ++nt) {
        f16x8 bfr = *(const f16x8*)(wq_h + (ncb + nt * 16 + lcol) * 256 + kt * 32 + lq * 8);
#pragma unroll
        for (int mt = 0; mt < 4; ++mt)
          acc[mt][nt] = __builtin_amdgcn_mfma_f32_16x16x32_f16(afr[mt], bfr, acc[mt][nt], 0, 0, 0);
      }
    }
#pragma unroll
    for (int mt = 0; mt < 4; ++mt)
#pragma unroll
      for (int nt = 0; nt < 3; ++nt) {
        f16x4 hv;
        hv[0] = (f16)acc[mt][nt][0]; hv[1] = (f16)acc[mt][nt][1];
        hv[2] = (f16)acc[mt][nt][2]; hv[3] = (f16)acc[mt][nt][3];
        *(f16x4*)(qkvT + (ncb + nt * 16 + lcol) * FB_LDQ + mt * 16 + lq * 4) = hv;
      }
  }
  __syncthreads();
  {
    const int h = wv & 3, dh = wv >> 2, t = lane;
    float qreg[32];
#pragma unroll
    for (int dd = 0; dd < 32; ++dd)
      qreg[dd] = (float)qkvT[(h * 64 + dh * 32 + dd) * FB_LDQ + t];
#pragma unroll
    for (int g = 0; g < 4; ++g) {
      float s = 0.f;
#pragma unroll
      for (int dd = 0; dd < 32; ++dd)
        s += qreg[dd] * (float)qkvT[(256 + g * 64 + dh * 32 + dd) * FB_LDQ + t];
      spart[((dh * 4 + h) * 4 + g) * 64 + t] = s;
    }
  }
  __syncthreads();
  {
    const int h = wv & 3, dh = wv >> 2, t = lane;
    float P[4];
    float mx = -1e30f;
#pragma unroll
    for (int g = 0; g < 4; ++g) {
      float s = spart[(h * 4 + g) * 64 + t] + spart[((4 + h) * 4 + g) * 64 + t];
      s *= 0.125f;
      s = fminf(fmaxf(s, -10.f), 10.f);
      P[g] = s;
      mx = fmaxf(mx, s);
    }
    float sum = 0.f;
#pragma unroll
    for (int g = 0; g < 4; ++g) { P[g] = __expf(P[g] - mx); sum += P[g]; }
    float inv = 1.f / sum;
#pragma unroll
    for (int g = 0; g < 4; ++g) P[g] *= inv;
    const int row = h * 16 + (t >> 2);
    const int cb0 = (t & 3) * 128 + dh * 64;
#pragma unroll
    for (int db = 0; db < 32; db += 8) {
      f16x8 hv;
#pragma unroll
      for (int u = 0; u < 8; ++u) {
        int d = dh * 32 + db + u;
        float o = 0.f;
#pragma unroll
        for (int g = 0; g < 4; ++g)
          o += P[g] * (float)qkvT[(512 + g * 64 + d) * FB_LDQ + t];
        hv[u] = (f16)o;
      }
      *(f16x8*)fb_xwp(smem, row, cb0 + db * 2) = hv;
    }
  }
  __syncthreads();
  {
    f32x4 acc[4][2] = {};
    for (int kt = 0; kt < 8; ++kt) {
      f16x8 afr[4];
#pragma unroll
      for (int mt = 0; mt < 4; ++mt)
        afr[mt] = *(const f16x8*)fb_xwp(smem, mt * 16 + lcol, kt * 64 + lq * 16);
#pragma unroll
      for (int nt = 0; nt < 2; ++nt) {
        f16x8 bfr = *(const f16x8*)(wp_h + (wv * 32 + nt * 16 + lcol) * 256 + kt * 32 + lq * 8);
#pragma unroll
        for (int mt = 0; mt < 4; ++mt)
          acc[mt][nt] = __builtin_amdgcn_mfma_f32_16x16x32_f16(afr[mt], bfr, acc[mt][nt], 0, 0, 0);
      }
    }
    float* ob = out + (size_t)bw * 8388608 + iw * 4096 + jw * 128 + kw * 4;
#pragma unroll
    for (int mt = 0; mt < 4; ++mt) {
#pragma unroll
      for (int nt = 0; nt < 2; ++nt) {
        int c3 = wv * 32 + nt * 16 + lcol;
        float4 v;
        v.x = acc[mt][nt][0]; v.y = acc[mt][nt][1];
        v.z = acc[mt][nt][2]; v.w = acc[mt][nt][3];
        *(float4*)(ob + (size_t)c3 * 32768 + mt * 1024 + lq * 32) = v;
      }
    }
  }
}

extern "C" void kernel_launch(void* const* d_in, const int* in_sizes, int n_in,
                              void* d_out, int out_size, void* d_ws, size_t ws_size,
                              hipStream_t stream) {
  const float* x = (const float*)d_in[0];
  const float* wq = (const float*)d_in[1];
  const float* wp = (const float*)d_in[2];
  float* out = (float*)d_out;
  char* ws = (char*)d_ws;
  f16* wq_h = (f16*)(ws + WQH_OFF);
  f16* wp_h = (f16*)(ws + WPH_OFF);

  cvt_weights_k<<<1024, 256, 0, stream>>>(wq, wp, wq_h, wp_h);

  if (ws_size >= WS_NEED) {
    f16* xw_all = (f16*)(ws + XW_OFF);
    f16* o2T = (f16*)(ws + O2_OFF);
    (void)hipFuncSetAttribute((const void*)win_attn_k,
                              hipFuncAttributeMaxDynamicSharedMemorySize, SMEM_TOTAL);
    gather_k<<<4096, 256, 0, stream>>>(x, xw_all);
    win_attn_k<<<4096, 512, SMEM_TOTAL, stream>>>(xw_all, wq_h, wp_h, o2T);
    scatter_k<<<4096, 256, 0, stream>>>(o2T, out);
  } else {
    (void)hipFuncSetAttribute((const void*)fused_fb_k,
                              hipFuncAttributeMaxDynamicSharedMemorySize, FB_SMEM);
    fused_fb_k<<<2048, 512, FB_SMEM, stream>>>(x, wq_h, wp_h, out);
  }
}

// Round 12
// 270.625 us; speedup vs baseline: 1.4152x; 1.4152x over previous
//
#include <hip/hip_runtime.h>

typedef _Float16 f16;
typedef f16 f16x2 __attribute__((ext_vector_type(2)));
typedef f16 f16x4 __attribute__((ext_vector_type(4)));
typedef f16 f16x8 __attribute__((ext_vector_type(8)));
typedef float f32x4 __attribute__((ext_vector_type(4)));

union v8split { f16x8 v8; f16x2 v2[4]; };

// ---------------- d_ws layout ----------------
#define WQH_OFF 0
#define WPH_OFF (768 * 256 * 2)                         // 393216
#define XW_OFF  (WPH_OFF + 256 * 256 * 2)               // 524288
#define O2_OFF  (XW_OFF + (size_t)2048 * 16384 * 2)     // +67108864
#define WS_NEED (O2_OFF + (size_t)2048 * 16384 * 2)     // 134742016

// LDS: bufX (xw/out2) 32KB | qkv [64t][1536B] 96KB = 128KB -> 1 block/CU.
// Block = 1024 threads = 16 waves = 4 waves/SIMD (r10 had only 2/SIMD; the
// exposed L2 weight-load latency is the bottleneck -> double the contexts).
#define QKV_LDS_OFF 32768
#define SMEM_TOTAL 131072

// fp32 -> fp16 weight conversion
__global__ __launch_bounds__(256) void cvt_weights_k(
    const float* __restrict__ wq, const float* __restrict__ wp,
    f16* __restrict__ wq_h, f16* __restrict__ wp_h) {
  int idx = blockIdx.x * 256 + threadIdx.x;
  if (idx < 768 * 256) wq_h[idx] = (f16)wq[idx];
  else wp_h[idx - 768 * 256] = (f16)wp[idx - 768 * 256];
}

// XOR-swizzled addr into a 64-row x 512B tile (xw / out2) — r10-validated.
__device__ __forceinline__ char* xwp(char* s, int row, int colbyte) {
  return s + row * 512 + (colbyte ^ (((row ^ (row >> 3)) & 7) << 4));
}
// qkv tile [64 t][768 f], row stride 1536B — r10-validated.
__device__ __forceinline__ char* qvp(char* s, int t, int fbyte) {
  return s + QKV_LDS_OFF + t * 1536 + (fbyte ^ ((t & 7) << 4));
}

// DPP quad_perm swaps: lane^1 and lane^2 (r11-validated attention merge)
__device__ __forceinline__ float qswap1f(float v) {
  int x = __builtin_bit_cast(int, v);
  x = __builtin_amdgcn_update_dpp(0, x, 0xB1, 0xf, 0xf, true);  // [1,0,3,2]
  return __builtin_bit_cast(float, x);
}
__device__ __forceinline__ float qswap2f(float v) {
  int x = __builtin_bit_cast(int, v);
  x = __builtin_amdgcn_update_dpp(0, x, 0x4E, 0xf, 0xf, true);  // [2,3,0,1]
  return __builtin_bit_cast(float, x);
}

#if __has_builtin(__builtin_amdgcn_fdot2)
__device__ __forceinline__ float fdot2f(f16x2 a, f16x2 b, float c) {
  return __builtin_amdgcn_fdot2(a, b, c, false);
}
#else
__device__ __forceinline__ float fdot2f(f16x2 a, f16x2 b, float c) {
  return c + (float)a[0] * (float)b[0] + (float)a[1] * (float)b[1];
}
#endif

// ---- K1: gather/transpose x (fp32 strided, full 128B-line reads) -> xw_all
// (fp16, per-window contiguous 32KB, PRE-SWIZZLED to match xwp). r10 version.
__global__ __launch_bounds__(256) void gather_k(const float* __restrict__ x,
                                                f16* __restrict__ xw_all) {
  const int g = blockIdx.x >> 4, cb = blockIdx.x & 15;
  const int b = g >> 6, iw = (g >> 3) & 7, jw = g & 7;
  const int tid = threadIdx.x;
  const int c = cb * 16 + (tid >> 4), a = (tid >> 2) & 3, bb = tid & 3;
  const float* src = x + (size_t)b * 8388608 + (size_t)c * 32768 +
                     (iw * 4 + a) * 1024 + (jw * 4 + bb) * 32;
  const int t = c >> 2;
  const int c2b = (c & 3) * 128 + a * 32 + bb * 8;
  const int byt = t * 512 + (c2b ^ (((t ^ (t >> 3)) & 7) << 4));
  char* wbase = (char*)(xw_all + (size_t)(g << 3) * 16384) + byt;
#pragma unroll
  for (int kw = 0; kw < 8; ++kw) {
    float4 v = *(const float4*)(src + kw * 4);
    f16x4 h;
    h[0] = (f16)v.x; h[1] = (f16)v.y; h[2] = (f16)v.z; h[3] = (f16)v.w;
    *(f16x4*)(wbase + kw * 32768) = h;
  }
}

// ---- K2: fused per-window kernel. One window per block, 2048 blocks,
// 1024 threads (16 waves -> 4/SIMD), 128KB LDS. Phases: xw->LDS, GEMM1
// (wave = 48 f-cols), per-token attention (wave = 4 tokens), GEMM2
// (wave = 16 c3-cols) -> o2T.
__global__ __launch_bounds__(1024) void win_attn_k(
    const f16* __restrict__ xw_all, const f16* __restrict__ wq_h,
    const f16* __restrict__ wp_h, f16* __restrict__ o2T) {
  extern __shared__ char smem[];
  const int wi = blockIdx.x;
  const int tid = threadIdx.x, wv = tid >> 6, lane = tid & 63;
  const int lcol = lane & 15, lq = lane >> 4;

  // Phase 1: 32KB pre-swizzled xw -> LDS (linear dest, 2x16B per thread).
  {
    const char* g = (const char*)(xw_all + (size_t)wi * 16384) + tid * 16;
    __builtin_amdgcn_global_load_lds(
        (const __attribute__((address_space(1))) void*)(g),
        (__attribute__((address_space(3))) void*)(smem + tid * 16), 16, 0, 0);
    __builtin_amdgcn_global_load_lds(
        (const __attribute__((address_space(1))) void*)(g + 16384),
        (__attribute__((address_space(3))) void*)(smem + tid * 16 + 16384), 16, 0, 0);
  }
  __syncthreads();

  // Phase 2: GEMM1 qkv[64t x 768f]. Wave = 48 f-cols, single acc[3][4] pass.
  {
    f32x4 acc[3][4] = {};
    const int fs = wv * 48;
#pragma unroll
    for (int kt = 0; kt < 8; ++kt) {
      f16x8 bf[4];
#pragma unroll
      for (int nt = 0; nt < 4; ++nt)
        bf[nt] = *(const f16x8*)xwp(smem, nt * 16 + lcol, kt * 64 + lq * 16);
#pragma unroll
      for (int ms = 0; ms < 3; ++ms) {
        f16x8 af = *(const f16x8*)(wq_h + (size_t)(fs + ms * 16 + lcol) * 256 + kt * 32 + lq * 8);
#pragma unroll
        for (int nt = 0; nt < 4; ++nt)
          acc[ms][nt] = __builtin_amdgcn_mfma_f32_16x16x32_f16(af, bf[nt], acc[ms][nt], 0, 0, 0);
      }
    }
    // D: col(lane&15)=token, row(lq*4+r)=feature -> f16x4 to qkv[t][f].
#pragma unroll
    for (int ms = 0; ms < 3; ++ms)
#pragma unroll
      for (int nt = 0; nt < 4; ++nt) {
        f16x4 hv;
        hv[0] = (f16)acc[ms][nt][0]; hv[1] = (f16)acc[ms][nt][1];
        hv[2] = (f16)acc[ms][nt][2]; hv[3] = (f16)acc[ms][nt][3];
        *(f16x4*)qvp(smem, nt * 16 + lcol, (fs + ms * 16 + lq * 4) * 2) = hv;
      }
  }
  __syncthreads();

  // Phase 3: per-token attention. Wave owns 4 tokens; lane = (tt<<4|h<<2|dq):
  // lane covers a 16-half d-quarter; S merged via lane^1 then lane^2 DPP.
  {
    const int tt = lane >> 4, h = (lane >> 2) & 3, dq = lane & 3;
    const int t = wv * 4 + tt;
    const int db = dq * 32;  // byte offset of this lane's d-quarter

    f16x2 q2[8];
#pragma unroll
    for (int j = 0; j < 2; ++j) {
      v8split u;
      u.v8 = *(const f16x8*)qvp(smem, t, h * 128 + db + j * 16);
      q2[j * 4 + 0] = u.v2[0]; q2[j * 4 + 1] = u.v2[1];
      q2[j * 4 + 2] = u.v2[2]; q2[j * 4 + 3] = u.v2[3];
    }
    float s[4];
#pragma unroll
    for (int g = 0; g < 4; ++g) {
      float a = 0.f;
#pragma unroll
      for (int j = 0; j < 2; ++j) {
        v8split u;
        u.v8 = *(const f16x8*)qvp(smem, t, 512 + g * 128 + db + j * 16);
        a = fdot2f(q2[j * 4 + 0], u.v2[0], a);
        a = fdot2f(q2[j * 4 + 1], u.v2[1], a);
        a = fdot2f(q2[j * 4 + 2], u.v2[2], a);
        a = fdot2f(q2[j * 4 + 3], u.v2[3], a);
      }
      s[g] = a;
    }
#pragma unroll
    for (int g = 0; g < 4; ++g) {
      s[g] += qswap1f(s[g]);   // merge dq^1
      s[g] += qswap2f(s[g]);   // merge dq^2 -> full 64-d dot on all 4 lanes
    }

    float mx = -1e30f;
#pragma unroll
    for (int g = 0; g < 4; ++g) {
      float v = fminf(fmaxf(s[g] * 0.125f, -10.f), 10.f);  // clip BEFORE softmax
      s[g] = v; mx = fmaxf(mx, v);
    }
    float sum = 0.f;
#pragma unroll
    for (int g = 0; g < 4; ++g) { s[g] = __expf(s[g] - mx); sum += s[g]; }
    float inv = 1.f / sum;
#pragma unroll
    for (int g = 0; g < 4; ++g) s[g] *= inv;

    float o[16] = {};
#pragma unroll
    for (int g = 0; g < 4; ++g) {
      float p = s[g];
#pragma unroll
      for (int j = 0; j < 2; ++j) {
        v8split u;
        u.v8 = *(const f16x8*)qvp(smem, t, 1024 + g * 128 + db + j * 16);
#pragma unroll
        for (int i = 0; i < 4; ++i) {
          o[j * 8 + 2 * i]     += p * (float)u.v2[i][0];
          o[j * 8 + 2 * i + 1] += p * (float)u.v2[i][1];
        }
      }
    }
    // out2 row = h*16 + t/4, colbyte = (t&3)*128 + dq*32 + j*16; reuse bufX.
    const int row = h * 16 + (t >> 2);
    const int cb0 = (t & 3) * 128 + db;
#pragma unroll
    for (int j = 0; j < 2; ++j) {
      f16x8 ov;
      ov[0] = (f16)o[j * 8 + 0]; ov[1] = (f16)o[j * 8 + 1];
      ov[2] = (f16)o[j * 8 + 2]; ov[3] = (f16)o[j * 8 + 3];
      ov[4] = (f16)o[j * 8 + 4]; ov[5] = (f16)o[j * 8 + 5];
      ov[6] = (f16)o[j * 8 + 6]; ov[7] = (f16)o[j * 8 + 7];
      *(f16x8*)xwp(smem, row, cb0 + j * 16) = ov;
    }
  }
  __syncthreads();

  // Phase 4: GEMM2 final[64x256] = out2 @ w_proj^T. Wave = 16 c3-cols.
  {
    f32x4 acc2[4] = {};
    const int c3 = wv * 16 + lcol;
    const f16* bp = wp_h + (size_t)c3 * 256;
#pragma unroll
    for (int kt = 0; kt < 8; ++kt) {
      f16x8 bfr = *(const f16x8*)(bp + kt * 32 + lq * 8);
#pragma unroll
      for (int mt = 0; mt < 4; ++mt) {
        f16x8 afr = *(const f16x8*)xwp(smem, mt * 16 + lcol, kt * 64 + lq * 16);
        acc2[mt] = __builtin_amdgcn_mfma_f32_16x16x32_f16(afr, bfr, acc2[mt], 0, 0, 0);
      }
    }
    // D: col = c3, row = token t2 = mt*16 + lq*4 + r -> o2T[c3][t2].
    f16* ob = o2T + (size_t)wi * 16384;
#pragma unroll
    for (int mt = 0; mt < 4; ++mt) {
      f16x4 hv;
      hv[0] = (f16)acc2[mt][0]; hv[1] = (f16)acc2[mt][1];
      hv[2] = (f16)acc2[mt][2]; hv[3] = (f16)acc2[mt][3];
      *(f16x4*)(ob + c3 * 64 + mt * 16 + lq * 4) = hv;
    }
  }
}

// ---- K3: scatter o2T (fp16, L3-hot) -> out (fp32, full 128B-line writes).
__global__ __launch_bounds__(256) void scatter_k(const f16* __restrict__ o2T,
                                                 float* __restrict__ out) {
  const int g = blockIdx.x >> 4, cb = blockIdx.x & 15;
  const int b = g >> 6, iw = (g >> 3) & 7, jw = g & 7;
  const int tid = threadIdx.x;
  const int c3 = cb * 16 + (tid >> 4), a = (tid >> 2) & 3, bb = tid & 3;
  const f16* rbase = o2T + (size_t)(g << 3) * 16384 + c3 * 64 + a * 16 + bb * 4;
  float* dst = out + (size_t)b * 8388608 + (size_t)c3 * 32768 +
               (iw * 4 + a) * 1024 + (jw * 4 + bb) * 32;
#pragma unroll
  for (int kw = 0; kw < 8; ++kw) {
    f16x4 h = *(const f16x4*)(rbase + kw * 16384);
    float4 v;
    v.x = (float)h[0]; v.y = (float)h[1]; v.z = (float)h[2]; v.w = (float)h[3];
    *(float4*)(dst + kw * 4) = v;
  }
}

// ================= fallback: round-1 fused kernel (validated, ws-light) =====
#define FB_LDQ 68
#define FB_QKV_OFF 32768
#define FB_SPART_OFF (FB_QKV_OFF + 768 * FB_LDQ * 2)
#define FB_SMEM (FB_SPART_OFF + 32 * 64 * 4)

__device__ __forceinline__ char* fb_xwp(char* s, int row, int colbyte) {
  return s + row * 512 + (colbyte ^ ((row & 7) << 4));
}

__global__ __launch_bounds__(512) void fused_fb_k(
    const float* __restrict__ x, const f16* __restrict__ wq_h,
    const f16* __restrict__ wp_h, float* __restrict__ out) {
  extern __shared__ char smem[];
  f16* qkvT = (f16*)(smem + FB_QKV_OFF);
  float* spart = (float*)(smem + FB_SPART_OFF);
  const int tid = threadIdx.x;
  const int wi = blockIdx.x;
  const int kw = wi & 7, jw = (wi >> 3) & 7, iw = (wi >> 6) & 7, bw = wi >> 9;
  const float* xb = x + (size_t)bw * 8388608 + iw * 4096 + jw * 128 + kw * 4;
#pragma unroll
  for (int it = 0; it < 8; ++it) {
    int idx = it * 512 + tid;
    int c = idx >> 4, a = (idx >> 2) & 3, bb = idx & 3;
    float4 v = *(const float4*)(xb + (size_t)c * 32768 + a * 1024 + bb * 32);
    f16x4 h;
    h[0] = (f16)v.x; h[1] = (f16)v.y; h[2] = (f16)v.z; h[3] = (f16)v.w;
    *(f16x4*)fb_xwp(smem, c >> 2, (c & 3) * 128 + a * 32 + bb * 8) = h;
  }
  __syncthreads();
  const int wv = tid >> 6, lane = tid & 63;
  const int lcol = lane & 15, lq = lane >> 4;
  for (int nc = 0; nc < 2; ++nc) {
    const int ncb = wv * 96 + nc * 48;
    f32x4 acc[4][3] = {};
    for (int kt = 0; kt < 8; ++kt) {
      f16x8 afr[4];
#pragma unroll
      for (int mt = 0; mt < 4; ++mt)
        afr[mt] = *(const f16x8*)fb_xwp(smem, mt * 16 + lcol, kt * 64 + lq * 16);
#pragma unroll
      for (int nt = 0; nt < 3; ++nt) {
        f16x8 bfr = *(const f16x8*)(wq_h + (ncb + nt * 16 + lcol) * 256 + kt * 32 + lq * 8);
#pragma unroll
        for (int mt = 0; mt < 4; ++mt)
          acc[mt][nt] = __builtin_amdgcn_mfma_f32_16x16x32_f16(afr[mt], bfr, acc[mt][nt], 0, 0, 0);
      }
    }
#pragma unroll
    for (int mt = 0; mt < 4; ++mt)
#pragma unroll
      for (int nt = 0; nt < 3; ++nt) {
        f16x4 hv;
        hv[0] = (f16)acc[mt][nt][0]; hv[1] = (f16)acc[mt][nt][1];
        hv[2] = (f16)acc[mt][nt][2]; hv[3] = (f16)acc[mt][nt][3];
        *(f16x4*)(qkvT + (ncb + nt * 16 + lcol) * FB_LDQ + mt * 16 + lq * 4) = hv;
      }
  }
  __syncthreads();
  {
    const int h = wv & 3, dh = wv >> 2, t = lane;
    float qreg[32];
#pragma unroll
    for (int dd = 0; dd < 32; ++dd)
      qreg[dd] = (float)qkvT[(h * 64 + dh * 32 + dd) * FB_LDQ + t];
#pragma unroll
    for (int g = 0; g < 4; ++g) {
      float s = 0.f;
#pragma unroll
      for (int dd = 0; dd < 32; ++dd)
        s += qreg[dd] * (float)qkvT[(256 + g * 64 + dh * 32 + dd) * FB_LDQ + t];
      spart[((dh * 4 + h) * 4 + g) * 64 + t] = s;
    }
  }
  __syncthreads();
  {
    const int h = wv & 3, dh = wv >> 2, t = lane;
    float P[4];
    float mx = -1e30f;
#pragma unroll
    for (int g = 0; g < 4; ++g) {
      float s = spart[(h * 4 + g) * 64 + t] + spart[((4 + h) * 4 + g) * 64 + t];
      s *= 0.125f;
      s = fminf(fmaxf(s, -10.f), 10.f);
      P[g] = s;
      mx = fmaxf(mx, s);
    }
    float sum = 0.f;
#pragma unroll
    for (int g = 0; g < 4; ++g) { P[g] = __expf(P[g] - mx); sum += P[g]; }
    float inv = 1.f / sum;
#pragma unroll
    for (int g = 0; g < 4; ++g) P[g] *= inv;
    const int row = h * 16 + (t >> 2);
    const int cb0 = (t & 3) * 128 + dh * 64;
#pragma unroll
    for (int db = 0; db < 32; db += 8) {
      f16x8 hv;
#pragma unroll
      for (int u = 0; u < 8; ++u) {
        int d = dh * 32 + db + u;
        float o = 0.f;
#pragma unroll
        for (int g = 0; g < 4; ++g)
          o += P[g] * (float)qkvT[(512 + g * 64 + d) * FB_LDQ + t];
        hv[u] = (f16)o;
      }
      *(f16x8*)fb_xwp(smem, row, cb0 + db * 2) = hv;
    }
  }
  __syncthreads();
  {
    f32x4 acc[4][2] = {};
    for (int kt = 0; kt < 8; ++kt) {
      f16x8 afr[4];
#pragma unroll
      for (int mt = 0; mt < 4; ++mt)
        afr[mt] = *(const f16x8*)fb_xwp(smem, mt * 16 + lcol, kt * 64 + lq * 16);
#pragma unroll
      for (int nt = 0; nt < 2; ++nt) {
        f16x8 bfr = *(const f16x8*)(wp_h + (wv * 32 + nt * 16 + lcol) * 256 + kt * 32 + lq * 8);
#pragma unroll
        for (int mt = 0; mt < 4; ++mt)
          acc[mt][nt] = __builtin_amdgcn_mfma_f32_16x16x32_f16(afr[mt], bfr, acc[mt][nt], 0, 0, 0);
      }
    }
    float* ob = out + (size_t)bw * 8388608 + iw * 4096 + jw * 128 + kw * 4;
#pragma unroll
    for (int mt = 0; mt < 4; ++mt) {
#pragma unroll
      for (int nt = 0; nt < 2; ++nt) {
        int c3 = wv * 32 + nt * 16 + lcol;
        float4 v;
        v.x = acc[mt][nt][0]; v.y = acc[mt][nt][1];
        v.z = acc[mt][nt][2]; v.w = acc[mt][nt][3];
        *(float4*)(ob + (size_t)c3 * 32768 + mt * 1024 + lq * 32) = v;
      }
    }
  }
}

extern "C" void kernel_launch(void* const* d_in, const int* in_sizes, int n_in,
                              void* d_out, int out_size, void* d_ws, size_t ws_size,
                              hipStream_t stream) {
  const float* x = (const float*)d_in[0];
  const float* wq = (const float*)d_in[1];
  const float* wp = (const float*)d_in[2];
  float* out = (float*)d_out;
  char* ws = (char*)d_ws;
  f16* wq_h = (f16*)(ws + WQH_OFF);
  f16* wp_h = (f16*)(ws + WPH_OFF);

  cvt_weights_k<<<1024, 256, 0, stream>>>(wq, wp, wq_h, wp_h);

  if (ws_size >= WS_NEED) {
    f16* xw_all = (f16*)(ws + XW_OFF);
    f16* o2T = (f16*)(ws + O2_OFF);
    (void)hipFuncSetAttribute((const void*)win_attn_k,
                              hipFuncAttributeMaxDynamicSharedMemorySize, SMEM_TOTAL);
    gather_k<<<4096, 256, 0, stream>>>(x, xw_all);
    win_attn_k<<<2048, 1024, SMEM_TOTAL, stream>>>(xw_all, wq_h, wp_h, o2T);
    scatter_k<<<4096, 256, 0, stream>>>(o2T, out);
  } else {
    (void)hipFuncSetAttribute((const void*)fused_fb_k,
                              hipFuncAttributeMaxDynamicSharedMemorySize, FB_SMEM);
    fused_fb_k<<<2048, 512, FB_SMEM, stream>>>(x, wq_h, wp_h, out);
  }
}